// Round 23
// baseline (133.469 us; speedup 1.0000x reference)
//
#include <hip/hip_runtime.h>
#include <hip/hip_bf16.h>

#define F 64
#define RB 128            // nodes per bucket (power of 2)
#define RBSH 7
#define NBMAX 800         // N=100000 -> NB=782
#define CHUNKA 4096       // edges per passA block (1024 threads, 4/thread)
#define CAPR  2816        // rec capacity per bucket (mean 2048, sigma 45: 17σ)
#define CAPL  3200        // LDS record slots: CAPR + 3*RB pad = 3200

typedef int            nt_int4   __attribute__((ext_vector_type(4)));
typedef float          nt_float4 __attribute__((ext_vector_type(4)));

__device__ __forceinline__ unsigned short f2bf(float f) {
    unsigned int u = __float_as_uint(f);
    unsigned int r = (u + 0x7FFFu + ((u >> 16) & 1u)) >> 16;   // RNE
    return (unsigned short)r;
}
__device__ __forceinline__ unsigned int pack2bf(float lo, float hi) {
    return (unsigned int)f2bf(lo) | ((unsigned int)f2bf(hi) << 16);
}

// ---------------------------------------------------------------------------
// Stage 1: EvolveGCN-O GRU on the [64,64] weight -> W_new transposed.
// Also initializes gcur (blocks 0..3) — stream order guarantees completion
// before the fused xw/passA kernel.
// ---------------------------------------------------------------------------
__global__ void evolve_kernel(const float* __restrict__ W,
                              const float* __restrict__ wih,
                              const float* __restrict__ whh,
                              const float* __restrict__ bih,
                              const float* __restrict__ bhh,
                              float* __restrict__ wt,
                              int* __restrict__ gcur, int NB) {
    if (blockIdx.x < 4) {
        int gi = blockIdx.x * 256 + threadIdx.x;
        if (gi < NB) gcur[gi] = gi * CAPR;
    }
    int t = blockIdx.x * blockDim.x + threadIdx.x;
    if (t >= F * F) return;
    int i = t >> 6;
    int j = t & 63;
    const float* Wi = W + i * F;
    float gxr = bih[j], gxz = bih[F + j], gxn = bih[2 * F + j];
    float ghr = bhh[j], ghz = bhh[F + j], ghn = bhh[2 * F + j];
#pragma unroll
    for (int k = 0; k < F; ++k) {
        float wv = Wi[k];
        gxr += wv * wih[(j) * F + k];
        gxz += wv * wih[(F + j) * F + k];
        gxn += wv * wih[(2 * F + j) * F + k];
        ghr += wv * whh[(j) * F + k];
        ghz += wv * whh[(F + j) * F + k];
        ghn += wv * whh[(2 * F + j) * F + k];
    }
    float r = 1.0f / (1.0f + expf(-(gxr + ghr)));
    float z = 1.0f / (1.0f + expf(-(gxz + ghz)));
    float n = tanhf(gxn + r * ghn);
    float wnew = (1.0f - z) * n + z * Wi[j];
    wt[j * F + i] = wnew;                      // transposed: wt[col][k]
}

// ---------------------------------------------------------------------------
// Stage 2+3 FUSED (xw ∥ passA): xw and passA are data-independent — even
// blocks (first 2*CA) run passA, odd blocks run xw, interleaved across XCDs.
// xw is FMA-bound, passA is atomic/scatter-bound -> complementary pipes;
// the fused kernel should cost ~max(xw, passA) instead of the sum.
//
// xw body (1024 rows/block, XCD-aligned swizzle, r16-proven math):
//   xw16 = bf16( rsqrt(deg) * (x @ W_new) ), 4-way column split, W reads
//   block-uniform -> SGPR broadcast, 2x16B back-to-back stores.
// passA body (r20-proven): bucketed scatter, per-(block,bucket) contiguous
//   runs into fixed-capacity buckets; edge triples register-cached.
//   Record: [dl:7 | src:17 | w:15] in u64.
// ---------------------------------------------------------------------------
__global__ void __launch_bounds__(1024) fused_kernel(
        const float* __restrict__ x,
        const float* __restrict__ wt,
        const float* __restrict__ deg,
        unsigned short* __restrict__ xw16,
        const int* __restrict__ ei, const float* __restrict__ ew,
        int* __restrict__ gcur,
        unsigned long long* __restrict__ rec,
        int N, int E, int NB, int CA, int NXW) {
    __shared__ int lh[NBMAX];
    __shared__ int lcur[NBMAX];
    int bid = blockIdx.x;
    bool is_xw;
    int idx;
    if (bid < 2 * CA) { is_xw = (bid & 1); idx = bid >> 1; }
    else              { is_xw = true;      idx = CA + (bid - 2 * CA); }
    int t = threadIdx.x;

    if (!is_xw) {
        // ---------------- passA body ----------------
        for (int i = t; i < NB; i += 1024) lh[i] = 0;
        __syncthreads();
        int base = idx * CHUNKA;
        int  dstR[4], srcR[4];
        float ewR[4];
        bool ok[4];
#pragma unroll
        for (int it = 0; it < CHUNKA / 1024; ++it) {
            int e = base + it * 1024 + t;
            ok[it] = (e < E);
            if (ok[it]) {
                dstR[it] = ei[E + e];
                srcR[it] = ei[e];
                ewR[it]  = ew[e];
                atomicAdd(&lh[dstR[it] >> RBSH], 1);
            }
        }
        __syncthreads();
        for (int i = t; i < NB; i += 1024) {
            int c = lh[i];
            lcur[i] = c ? atomicAdd(&gcur[i], c) : 0;
        }
        __syncthreads();
#pragma unroll
        for (int it = 0; it < CHUNKA / 1024; ++it) {
            if (ok[it]) {
                unsigned int q = (unsigned int)(ewR[it] * 32767.0f + 0.5f);
                int b = dstR[it] >> RBSH;
                int p = atomicAdd(&lcur[b], 1);
                unsigned long long r = ((unsigned long long)(dstR[it] & (RB - 1)) << 32)
                                     | ((unsigned long long)((unsigned int)srcR[it]) << 15) | q;
                rec[p] = r;
            }
        }
    } else {
        // ---------------- xw body (1024 rows/block) ----------------
        if (idx >= NXW) return;
        int a  = idx >> 5;
        int q4 = (idx >> 3) & 3;                  // quarter
        int bb = idx & 7;
        int rowblk = a * 8 + bb;                  // XCD-aligned: same bb -> same XCD
        int r = rowblk * 1024 + t;
        if (r >= N) return;
        float xr[F];
        const nt_float4* xp = (const nt_float4*)(x + (size_t)r * F);
#pragma unroll
        for (int q = 0; q < F / 4; ++q) {
            nt_float4 v = xp[q];                  // cached: reused by 4 quarters
            xr[4 * q + 0] = v.x; xr[4 * q + 1] = v.y;
            xr[4 * q + 2] = v.z; xr[4 * q + 3] = v.w;
        }
        float dinv = rsqrtf(deg[r]);
        const float* wbase = wt + q4 * 16 * F;    // wt[col][k], block-uniform
        unsigned int o[8];                        // 32B of packed bf16 outputs
#pragma unroll
        for (int cb = 0; cb < 4; ++cb) {          // 4 cols per cb
            const float* w0 = wbase + (4 * cb) * F;
            float a0 = 0.f, a1 = 0.f, a2 = 0.f, a3 = 0.f;
#pragma unroll
            for (int k = 0; k < F; ++k) {
                float xv = xr[k];
                a0 += xv * w0[k];
                a1 += xv * w0[F + k];
                a2 += xv * w0[2 * F + k];
                a3 += xv * w0[3 * F + k];
            }
            o[2 * cb]     = pack2bf(a0 * dinv, a1 * dinv);
            o[2 * cb + 1] = pack2bf(a2 * dinv, a3 * dinv);
        }
        nt_int4* dst = (nt_int4*)(xw16 + (size_t)r * F + q4 * 16);
#pragma unroll
        for (int q = 0; q < 2; ++q) {
            nt_int4 v;
            v.x = (int)o[4 * q + 0]; v.y = (int)o[4 * q + 1];
            v.z = (int)o[4 * q + 2]; v.w = (int)o[4 * q + 3];
            dst[q] = v;
        }
    }
}

// ---------------------------------------------------------------------------
// Stage 4 (sortsum): block per bucket, 512 threads — fused sortB + segsum
// (r22-proven, 43us). Phase 1: counting-sort bucket records by dl into LDS
// (4B records, padded x4 with zeros). Phase 2: 8 waves x 16 nodes; 16
// lanes/edge, 4 features/lane; record reads are LDS broadcasts; only the
// xw16 gather goes to global. Zero-pad records gather row 0 with q=0.
// ---------------------------------------------------------------------------
__global__ void __launch_bounds__(512) sortsum_kernel(
        const unsigned long long* __restrict__ rec,
        const int* __restrict__ gcur,
        const unsigned short* __restrict__ xw16,
        const float* __restrict__ deg,
        const float* __restrict__ lw,
        const float* __restrict__ lb,
        float* __restrict__ out, int M) {
    __shared__ unsigned int s_rec[CAPL];   // 12.8KB sorted 4B records
    __shared__ int cnt[RB];
    __shared__ int pex[RB];                // padded exclusive offsets
    __shared__ int cur[RB];                // write cursors
    int b = blockIdx.x;
    int t = threadIdx.x;                   // 512 threads
    int beg = b * CAPR;
    int end = gcur[b];                     // beg + count (passA's cursor)

    for (int i = t; i < CAPL; i += 512) s_rec[i] = 0u;
    if (t < RB) cnt[t] = 0;
    __syncthreads();

    for (int i = beg + t; i < end; i += 512)
        atomicAdd(&cnt[(int)(rec[i] >> 32)], 1);
    __syncthreads();

    if (t < RB) pex[t] = (cnt[t] + 3) & ~3;
    __syncthreads();
    for (int o = 1; o < RB; o <<= 1) {
        int v = (t < RB && t >= o) ? pex[t - o] : 0;
        __syncthreads();
        if (t < RB) pex[t] += v;
        __syncthreads();
    }
    if (t < RB) {
        int pcnt = (cnt[t] + 3) & ~3;
        int excl = pex[t] - pcnt;
        pex[t] = excl;
        cur[t] = excl;
    }
    __syncthreads();

    for (int i = beg + t; i < end; i += 512) {
        unsigned long long r = rec[i];
        int dl = (int)(r >> 32);
        int p = atomicAdd(&cur[dl], 1);
        s_rec[p] = (unsigned int)r;        // [src:17|w:15]
    }
    __syncthreads();

    int lane = t & 63;
    int wv = t >> 6;
    int eg = lane >> 4;                    // edge group 0..3
    int fq = lane & 15;                    // feature quad
    unsigned int flo = (unsigned int)(fq << 3);
    const char* xb = (const char*)xw16;
    float lw0 = lw[4 * fq + 0], lw1 = lw[4 * fq + 1];
    float lw2 = lw[4 * fq + 2], lw3 = lw[4 * fq + 3];
    const float esc = 1.0f / 32767.0f;
    int node0 = b << RBSH;
    for (int nl = wv; nl < RB; nl += 8) {
        int node = node0 + nl;
        if (node >= M) break;
        int nbeg = pex[nl];                // LDS
        int iters = (cnt[nl] + 3) >> 2;    // LDS
        float a0 = 0.f, a1 = 0.f, a2 = 0.f, a3 = 0.f;
#pragma unroll 4
        for (int i = 0; i < iters; ++i) {
            unsigned int r = s_rec[nbeg + 4 * i + eg];
            unsigned int off = ((r >> 8) & 0xFFFFFF80u) + flo;
            uint2 u = *(const uint2*)(xb + off);
            float q = (float)(r & 32767u);
            a0 += q * __uint_as_float(u.x << 16);
            a1 += q * __uint_as_float(u.x & 0xFFFF0000u);
            a2 += q * __uint_as_float(u.y << 16);
            a3 += q * __uint_as_float(u.y & 0xFFFF0000u);
        }
        a0 += __shfl_xor(a0, 16, 64); a0 += __shfl_xor(a0, 32, 64);
        a1 += __shfl_xor(a1, 16, 64); a1 += __shfl_xor(a1, 32, 64);
        a2 += __shfl_xor(a2, 16, 64); a2 += __shfl_xor(a2, 32, 64);
        a3 += __shfl_xor(a3, 16, 64); a3 += __shfl_xor(a3, 32, 64);
        float s = fmaxf(a0, 0.f) * lw0 + fmaxf(a1, 0.f) * lw1
                + fmaxf(a2, 0.f) * lw2 + fmaxf(a3, 0.f) * lw3;
#pragma unroll
        for (int o = 8; o; o >>= 1) s += __shfl_xor(s, o, 64);
        if (lane == 0) out[node] = s * (esc * rsqrtf(deg[node])) + lb[0];
    }
}

extern "C" void kernel_launch(void* const* d_in, const int* in_sizes, int n_in,
                              void* d_out, int out_size, void* d_ws, size_t ws_size,
                              hipStream_t stream) {
    const float* x   = (const float*)d_in[0];
    const int*   ei  = (const int*)d_in[1];
    const float* ew  = (const float*)d_in[2];
    const float* deg = (const float*)d_in[3];
    const float* W0  = (const float*)d_in[5];
    const float* wih = (const float*)d_in[6];
    const float* whh = (const float*)d_in[7];
    const float* bih = (const float*)d_in[8];
    const float* bhh = (const float*)d_in[9];
    const float* lw  = (const float*)d_in[10];
    const float* lb  = (const float*)d_in[11];
    float* out = (float*)d_out;

    int N = in_sizes[0] / F;        // 100000
    int E = in_sizes[1] / 2;        // 1600000
    int M = out_size;               // target_num
    int NB = (N + RB - 1) / RB;     // 782 (<= NBMAX, <= 1024)

    // workspace layout (fixed-capacity buckets; ~31MB total)
    float*              wt   = (float*)d_ws;                      // 8192 f (32KB)
    unsigned short*     xw16 = (unsigned short*)(wt + 8192);      // N*F bf16 (12.8MB)
    unsigned long long* rec  = (unsigned long long*)(xw16 + (size_t)N * F); // NB*CAPR u64 (17.6MB)
    int*                gcur = (int*)(rec + (size_t)NB * CAPR);   // NB

    evolve_kernel<<<(F * F + 255) / 256, 256, 0, stream>>>(W0, wih, whh, bih, bhh, wt, gcur, NB);

    {
        int CA   = (E + CHUNKA - 1) / CHUNKA;            // 391 passA chunks
        int nrb  = (N + 1023) / 1024;                    // 98 row blocks
        int nrb8 = (nrb + 7) & ~7;                       // 104 (pad to x8)
        int NXW  = 4 * nrb8;                             // 416 xw blocks
        int grid = 2 * CA + (NXW > CA ? NXW - CA : 0);   // 782 + 25 = 807
        fused_kernel<<<grid, 1024, 0, stream>>>(x, wt, deg, xw16, ei, ew,
                                                gcur, rec, N, E, NB, CA, NXW);
    }

    sortsum_kernel<<<NB, 512, 0, stream>>>(rec, gcur, xw16, deg, lw, lb, out, M);
}

// Round 25
// 116.907 us; speedup vs baseline: 1.1417x; 1.1417x over previous
//
#include <hip/hip_runtime.h>
#include <hip/hip_bf16.h>

#define F 64
#define RB 128            // nodes per bucket (power of 2)
#define RBSH 7
#define NBMAX 800         // N=100000 -> NB=782
#define CHUNKA 8192       // edges per passA block (1024 threads, 8/thread)
#define CAPR  2816        // rec capacity per bucket (mean 2048, sigma 45: 17σ)
#define CAPL  3200        // LDS record slots: CAPR + 3*RB pad = 3200
#define RCC   6           // sortsum reg-cache: ceil(CAPR/512)

typedef int            nt_int4   __attribute__((ext_vector_type(4)));
typedef float          nt_float4 __attribute__((ext_vector_type(4)));

__device__ __forceinline__ unsigned short f2bf(float f) {
    unsigned int u = __float_as_uint(f);
    unsigned int r = (u + 0x7FFFu + ((u >> 16) & 1u)) >> 16;   // RNE
    return (unsigned short)r;
}
__device__ __forceinline__ unsigned int pack2bf(float lo, float hi) {
    return (unsigned int)f2bf(lo) | ((unsigned int)f2bf(hi) << 16);
}

// ---------------------------------------------------------------------------
// Stage 1: EvolveGCN-O GRU on the [64,64] weight -> W_new transposed.
// Also initializes gcur (blocks 0..3) — stream order guarantees completion
// before passA.
// ---------------------------------------------------------------------------
__global__ void evolve_kernel(const float* __restrict__ W,
                              const float* __restrict__ wih,
                              const float* __restrict__ whh,
                              const float* __restrict__ bih,
                              const float* __restrict__ bhh,
                              float* __restrict__ wt,
                              int* __restrict__ gcur, int NB) {
    if (blockIdx.x < 4) {
        int gi = blockIdx.x * 256 + threadIdx.x;
        if (gi < NB) gcur[gi] = gi * CAPR;
    }
    int t = blockIdx.x * blockDim.x + threadIdx.x;
    if (t >= F * F) return;
    int i = t >> 6;
    int j = t & 63;
    const float* Wi = W + i * F;
    float gxr = bih[j], gxz = bih[F + j], gxn = bih[2 * F + j];
    float ghr = bhh[j], ghz = bhh[F + j], ghn = bhh[2 * F + j];
#pragma unroll
    for (int k = 0; k < F; ++k) {
        float wv = Wi[k];
        gxr += wv * wih[(j) * F + k];
        gxz += wv * wih[(F + j) * F + k];
        gxn += wv * wih[(2 * F + j) * F + k];
        ghr += wv * whh[(j) * F + k];
        ghz += wv * whh[(F + j) * F + k];
        ghn += wv * whh[(2 * F + j) * F + k];
    }
    float r = 1.0f / (1.0f + expf(-(gxr + ghr)));
    float z = 1.0f / (1.0f + expf(-(gxz + ghz)));
    float n = tanhf(gxn + r * ghn);
    float wnew = (1.0f - z) * n + z * Wi[j];
    wt[j * F + i] = wnew;                      // transposed: wt[col][k]
}

// ---------------------------------------------------------------------------
// Stage 2: xw16 = bf16( rsqrt(deg[r]) * (x @ W_new) ).
// THREAD-PER-ROW, 4-way COLUMN SPLIT + XCD-aligned swizzle (r16/r22-proven).
// Cached x loads; W block-uniform -> SGPR broadcast; packed outputs,
// 2x16B back-to-back stores.
// ---------------------------------------------------------------------------
__global__ void __launch_bounds__(256, 1) xw_kernel(
        const float* __restrict__ x,
        const float* __restrict__ wt,
        const float* __restrict__ deg,
        unsigned short* __restrict__ xw16, int N) {
    int i = blockIdx.x;
    int rowblk  = (i >> 5) * 8 + (i & 7);
    int quarter = (i >> 3) & 3;
    int r = rowblk * 256 + threadIdx.x;
    if (r >= N) return;
    float xr[F];
    const nt_float4* xp = (const nt_float4*)(x + (size_t)r * F);
#pragma unroll
    for (int q = 0; q < F / 4; ++q) {
        nt_float4 v = xp[q];                     // cached: reused by 4 quarters
        xr[4 * q + 0] = v.x; xr[4 * q + 1] = v.y;
        xr[4 * q + 2] = v.z; xr[4 * q + 3] = v.w;
    }
    float dinv = rsqrtf(deg[r]);
    const float* wbase = wt + quarter * 16 * F;  // wt[col][k], block-uniform
    unsigned int o[8];                           // 32B of packed bf16 outputs
#pragma unroll
    for (int cb = 0; cb < 4; ++cb) {             // 4 cols per cb
        const float* w0 = wbase + (4 * cb) * F;
        float a0 = 0.f, a1 = 0.f, a2 = 0.f, a3 = 0.f;
#pragma unroll
        for (int k = 0; k < F; ++k) {
            float xv = xr[k];
            a0 += xv * w0[k];
            a1 += xv * w0[F + k];
            a2 += xv * w0[2 * F + k];
            a3 += xv * w0[3 * F + k];
        }
        o[2 * cb]     = pack2bf(a0 * dinv, a1 * dinv);
        o[2 * cb + 1] = pack2bf(a2 * dinv, a3 * dinv);
    }
    nt_int4* dst = (nt_int4*)(xw16 + (size_t)r * F + quarter * 16);
#pragma unroll
    for (int q = 0; q < 2; ++q) {
        nt_int4 v;
        v.x = (int)o[4 * q + 0]; v.y = (int)o[4 * q + 1];
        v.z = (int)o[4 * q + 2]; v.w = (int)o[4 * q + 3];
        dst[q] = v;
    }
}

// ---------------------------------------------------------------------------
// Stage 3 (passA): bucketed scatter with per-(block,bucket) contiguous runs
// into FIXED-CAPACITY buckets. CHUNKA=8192 @ 1024 threads: 196 blocks x 16
// waves = 3136 waves (~3/SIMD, above the r16 starvation point), runs double
// to 10.5 records (84B -> better line fill on scattered run writes), global
// reserve-atomics halve. Phase-3 re-reads the chunk (96KB, L2-hot).
// Record: [dl:7 | src:17 | w:15] in u64.
// ---------------------------------------------------------------------------
__global__ void __launch_bounds__(1024) passA_kernel(
        const int* __restrict__ ei, const float* __restrict__ ew,
        int* __restrict__ gcur,
        unsigned long long* __restrict__ rec, int E, int NB) {
    __shared__ int lh[NBMAX];
    __shared__ int lcur[NBMAX];
    int t = threadIdx.x;           // 1024 threads
    for (int i = t; i < NB; i += 1024) lh[i] = 0;
    __syncthreads();
    int base = blockIdx.x * CHUNKA;
#pragma unroll
    for (int it = 0; it < CHUNKA / 1024; ++it) {
        int e = base + it * 1024 + t;
        if (e < E) atomicAdd(&lh[ei[E + e] >> RBSH], 1);
    }
    __syncthreads();
    for (int i = t; i < NB; i += 1024) {
        int c = lh[i];
        lcur[i] = c ? atomicAdd(&gcur[i], c) : 0;
    }
    __syncthreads();
#pragma unroll
    for (int it = 0; it < CHUNKA / 1024; ++it) {
        int e = base + it * 1024 + t;
        if (e < E) {
            int dst = ei[E + e];
            int src = ei[e];
            float w = ew[e];
            unsigned int q = (unsigned int)(w * 32767.0f + 0.5f);
            int b = dst >> RBSH;
            int p = atomicAdd(&lcur[b], 1);
            unsigned long long r = ((unsigned long long)(dst & (RB - 1)) << 32)
                                 | ((unsigned long long)((unsigned int)src) << 15) | q;
            rec[p] = r;
        }
    }
}

// ---------------------------------------------------------------------------
// Stage 4 (sortsum): block per bucket, 512 threads — fused sortB + segsum
// (r22-proven 43us) + phase-1 REGISTER CACHE: the bucket's records are read
// from global ONCE (into 6 u64 regs/thread) and reused for both the
// histogram and the LDS scatter — removes the second 12.8MB rec scan.
// Phase 2 unchanged: 8 waves x 16 nodes; 16 lanes/edge, 4 features/lane;
// record reads are LDS broadcasts; only the xw16 gather goes to global.
// Zero-pad records gather row 0 with q=0: harmless.
// ---------------------------------------------------------------------------
__global__ void __launch_bounds__(512) sortsum_kernel(
        const unsigned long long* __restrict__ rec,
        const int* __restrict__ gcur,
        const unsigned short* __restrict__ xw16,
        const float* __restrict__ deg,
        const float* __restrict__ lw,
        const float* __restrict__ lb,
        float* __restrict__ out, int M) {
    __shared__ unsigned int s_rec[CAPL];   // 12.8KB sorted 4B records
    __shared__ int cnt[RB];
    __shared__ int pex[RB];                // padded exclusive offsets
    __shared__ int cur[RB];                // write cursors
    int b = blockIdx.x;
    int t = threadIdx.x;                   // 512 threads
    int beg = b * CAPR;
    int end = gcur[b];                     // beg + count (passA's cursor)

    for (int i = t; i < CAPL; i += 512) s_rec[i] = 0u;
    if (t < RB) cnt[t] = 0;
    __syncthreads();

    // phase 1a: single global read into registers + histogram by dl
    unsigned long long rc[RCC];
#pragma unroll
    for (int k = 0; k < RCC; ++k) {
        int i = beg + k * 512 + t;
        bool v = (i < end);
        rc[k] = v ? rec[i] : 0ull;
        if (v) atomicAdd(&cnt[(int)(rc[k] >> 32)], 1);
    }
    __syncthreads();

    // phase 1b: inclusive scan of padded counts (128-wide)
    if (t < RB) pex[t] = (cnt[t] + 3) & ~3;
    __syncthreads();
    for (int o = 1; o < RB; o <<= 1) {
        int v = (t < RB && t >= o) ? pex[t - o] : 0;
        __syncthreads();
        if (t < RB) pex[t] += v;
        __syncthreads();
    }
    if (t < RB) {
        int pcnt = (cnt[t] + 3) & ~3;
        int excl = pex[t] - pcnt;
        pex[t] = excl;
        cur[t] = excl;
    }
    __syncthreads();

    // phase 1c: scatter cached records into LDS, sorted by dl
#pragma unroll
    for (int k = 0; k < RCC; ++k) {
        int i = beg + k * 512 + t;
        if (i < end) {
            int dl = (int)(rc[k] >> 32);
            int p = atomicAdd(&cur[dl], 1);
            s_rec[p] = (unsigned int)rc[k];    // [src:17|w:15]
        }
    }
    __syncthreads();

    // phase 2: gather + accumulate, 8 waves x 16 nodes
    int lane = t & 63;
    int wv = t >> 6;
    int eg = lane >> 4;                    // edge group 0..3
    int fq = lane & 15;                    // feature quad
    unsigned int flo = (unsigned int)(fq << 3);
    const char* xb = (const char*)xw16;
    float lw0 = lw[4 * fq + 0], lw1 = lw[4 * fq + 1];
    float lw2 = lw[4 * fq + 2], lw3 = lw[4 * fq + 3];
    const float esc = 1.0f / 32767.0f;
    int node0 = b << RBSH;
    for (int nl = wv; nl < RB; nl += 8) {
        int node = node0 + nl;
        if (node >= M) break;
        int nbeg = pex[nl];                // LDS
        int iters = (cnt[nl] + 3) >> 2;    // LDS
        float a0 = 0.f, a1 = 0.f, a2 = 0.f, a3 = 0.f;
#pragma unroll 4
        for (int i = 0; i < iters; ++i) {
            unsigned int r = s_rec[nbeg + 4 * i + eg];
            unsigned int off = ((r >> 8) & 0xFFFFFF80u) + flo;
            uint2 u = *(const uint2*)(xb + off);
            float q = (float)(r & 32767u);
            a0 += q * __uint_as_float(u.x << 16);
            a1 += q * __uint_as_float(u.x & 0xFFFF0000u);
            a2 += q * __uint_as_float(u.y << 16);
            a3 += q * __uint_as_float(u.y & 0xFFFF0000u);
        }
        a0 += __shfl_xor(a0, 16, 64); a0 += __shfl_xor(a0, 32, 64);
        a1 += __shfl_xor(a1, 16, 64); a1 += __shfl_xor(a1, 32, 64);
        a2 += __shfl_xor(a2, 16, 64); a2 += __shfl_xor(a2, 32, 64);
        a3 += __shfl_xor(a3, 16, 64); a3 += __shfl_xor(a3, 32, 64);
        float s = fmaxf(a0, 0.f) * lw0 + fmaxf(a1, 0.f) * lw1
                + fmaxf(a2, 0.f) * lw2 + fmaxf(a3, 0.f) * lw3;
#pragma unroll
        for (int o = 8; o; o >>= 1) s += __shfl_xor(s, o, 64);
        if (lane == 0) out[node] = s * (esc * rsqrtf(deg[node])) + lb[0];
    }
}

extern "C" void kernel_launch(void* const* d_in, const int* in_sizes, int n_in,
                              void* d_out, int out_size, void* d_ws, size_t ws_size,
                              hipStream_t stream) {
    const float* x   = (const float*)d_in[0];
    const int*   ei  = (const int*)d_in[1];
    const float* ew  = (const float*)d_in[2];
    const float* deg = (const float*)d_in[3];
    const float* W0  = (const float*)d_in[5];
    const float* wih = (const float*)d_in[6];
    const float* whh = (const float*)d_in[7];
    const float* bih = (const float*)d_in[8];
    const float* bhh = (const float*)d_in[9];
    const float* lw  = (const float*)d_in[10];
    const float* lb  = (const float*)d_in[11];
    float* out = (float*)d_out;

    int N = in_sizes[0] / F;        // 100000
    int E = in_sizes[1] / 2;        // 1600000
    int M = out_size;               // target_num
    int NB = (N + RB - 1) / RB;     // 782 (<= NBMAX, <= 1024)

    // workspace layout (fixed-capacity buckets; ~31MB total)
    float*              wt   = (float*)d_ws;                      // 8192 f (32KB)
    unsigned short*     xw16 = (unsigned short*)(wt + 8192);      // N*F bf16 (12.8MB)
    unsigned long long* rec  = (unsigned long long*)(xw16 + (size_t)N * F); // NB*CAPR u64 (17.6MB)
    int*                gcur = (int*)(rec + (size_t)NB * CAPR);   // NB

    evolve_kernel<<<(F * F + 255) / 256, 256, 0, stream>>>(W0, wih, whh, bih, bhh, wt, gcur, NB);

    {
        int nrb8 = (((N + 255) / 256) + 7) & ~7;     // row blocks, padded to x8
        xw_kernel<<<4 * nrb8, 256, 0, stream>>>(x, wt, deg, xw16, N);
    }

    passA_kernel<<<(E + CHUNKA - 1) / CHUNKA, 1024, 0, stream>>>(ei, ew, gcur, rec, E, NB);

    sortsum_kernel<<<NB, 512, 0, stream>>>(rec, gcur, xw16, deg, lw, lb, out, M);
}